// Round 2
// baseline (464.513 us; speedup 1.0000x reference)
//
#include <hip/hip_runtime.h>
#include <math.h>

#define BB 64
#define RR 6912
#define II 8
#define CC 10
#define OO 16
#define RPB 64          // routes per block
#define NCH 108         // RR / RPB
#define NGRP 8          // 2-route MFMA groups per wave (16 routes/wave x 4 waves)
#define MRG_PAD 20      // merge row stride in floats (pad 16->20 vs bank conflicts)
#define LDSF (4*64*MRG_PAD + 4*64)   // 5376 floats = 21504 B; aliases 16 KB W tile

typedef _Float16 h2 __attribute__((ext_vector_type(2)));
typedef _Float16 half8 __attribute__((ext_vector_type(8)));
typedef float f32x16 __attribute__((ext_vector_type(16)));
union HV { int4 v; h2 h[4]; half8 h8; };

// ---------------- prep kernel ----------------
// blocks [0,432): transpose+cvt x[B][R][8] f32 -> xth[R][B][8] f16
// blocks [432,1512): W convert  W[c][r][i][o] f32 -> wh[c][r][o][i] f16
//                    (each block handles 64 routes = 8 sub-tiles, dbuf LDS)
// block 0 additionally zeroes the 3x10 pass-completion counters.
__global__ __launch_bounds__(256) void prep_kernel(
    const float* __restrict__ x, int4* __restrict__ xth4,
    const float4* __restrict__ w4, int4* __restrict__ wh4,
    int* __restrict__ cnt)
{
    __shared__ __align__(16) float4 lds4[64 * 34];   // 34816 B; wcvt aliases 4 KB
    const int t = threadIdx.x;
    const int bid = blockIdx.x;

    if (bid == 0 && t < 32) cnt[t] = 0;

    if (bid < 432) {
        // ---- transpose+cvt ----
        const int rblk = bid >> 2;
        const int bblk = bid & 3;
        const int r0 = rblk * 64, b0 = bblk * 16;
        {
            const int rl = t & 63;
            const int bl0 = t >> 6;
#pragma unroll
            for (int kb = 0; kb < 4; ++kb) {
                const int bl = kb * 4 + bl0;
                const float4* src = (const float4*)(x + ((size_t)(b0 + bl) * RR + (r0 + rl)) * II);
                lds4[rl * 34 + bl * 2 + 0] = src[0];
                lds4[rl * 34 + bl * 2 + 1] = src[1];
            }
        }
        __syncthreads();
        {
            const int bl = t & 15;
            const int rw0 = t >> 4;
#pragma unroll
            for (int kr = 0; kr < 4; ++kr) {
                const int rw = kr * 16 + rw0;
                float4 a = lds4[rw * 34 + bl * 2 + 0];
                float4 bq = lds4[rw * 34 + bl * 2 + 1];
                HV u;
                u.h[0] = h2{(_Float16)a.x,  (_Float16)a.y};
                u.h[1] = h2{(_Float16)a.z,  (_Float16)a.w};
                u.h[2] = h2{(_Float16)bq.x, (_Float16)bq.y};
                u.h[3] = h2{(_Float16)bq.z, (_Float16)bq.w};
                xth4[(size_t)(r0 + rw) * BB + (b0 + bl)] = u.v;
            }
        }
    } else {
        // ---- W convert: 8 sub-tiles of 8 routes, double-buffered LDS ----
        _Float16* wl = (_Float16*)lds4;
        const int wblk = bid - 432;          // 0..1079
        const int rp = t >> 5;
        const int i  = (t >> 2) & 7;
        const int o0 = (t & 3) * 4;
#pragma unroll 1
        for (int sb = 0; sb < 8; ++sb) {
            const int blk8 = wblk * 8 + sb;  // == c*864 + (r/8)
            const float4 v = w4[(size_t)blk8 * 256 + t];
            _Float16* wb = wl + (sb & 1) * 1024;
            wb[(rp * 16 + o0 + 0) * 8 + i] = (_Float16)v.x;
            wb[(rp * 16 + o0 + 1) * 8 + i] = (_Float16)v.y;
            wb[(rp * 16 + o0 + 2) * 8 + i] = (_Float16)v.z;
            wb[(rp * 16 + o0 + 3) * 8 + i] = (_Float16)v.w;
            __syncthreads();
            if (t < 128) wh4[(size_t)blk8 * 128 + t] = ((const int4*)wb)[t];
        }
    }
}

// ---------------- pass kernel (MFMA, fused combine) ----------------
// Per block: one (c, 64-route chunk). W tile staged once in LDS (16 KB, f16
// [r][o][i]). Each wave owns 16 routes = 8 groups of 2 routes packed
// block-diagonally into v_mfma_f32_32x32x16_f16 (layouts: see R1 notes).
// Epilogue stores per-chunk partials, then the LAST block of each class c
// (device-scope counter) performs the cross-chunk combine + squash and writes
// the per-iteration output consumed by the next stream-ordered pass.
template <int MODE>
__global__ __launch_bounds__(256, 4) void pass_kernel(
    const int4* __restrict__ xth4, const int4* __restrict__ wh4,
    const float* __restrict__ ov_in,
    float* __restrict__ pacc, float* __restrict__ pz,
    float* __restrict__ outw, int* __restrict__ cnt)
{
    __shared__ __align__(16) float lds[LDSF];
    __shared__ int islast;
    int4* wlds = (int4*)lds;

    // XCD-affinity swizzle (1080 = 8*135, bijective): the 10 c-blocks sharing
    // a chunk's x-tile land on one XCD's L2.
    const int bid = blockIdx.x;
    const int w = (bid & 7) * 135 + (bid >> 3);
    const int chunk = w / 10;
    const int c = w - chunk * 10;

    const int t = threadIdx.x;
    const int wv = t >> 6;
    const int l = t & 63;
    const int b = l & 31;
    const int hi = l >> 5;
    const int aquad = (l >> 4) & 1;
    const bool aact = (aquad == hi);

    // stage the 64-route W tile: 256 threads x 4 int4, coalesced
    {
        const int4* src = wh4 + (size_t)(c * (RR / 8) + chunk * 8) * 128;
#pragma unroll
        for (int k = 0; k < 4; ++k) wlds[k * 256 + t] = src[k * 256 + t];
    }

    float accA[8], accB[8];
#pragma unroll
    for (int j = 0; j < 8; ++j) { accA[j] = 0.f; accB[j] = 0.f; }
    float ZA = 0.f, ZB = 0.f;

    // ov gather: lane needs out_prev[b][o] for its 8 o-slots
    // o(j,hi) = (j&3) + 8*(j>>2) + 4*hi  -> two float4s at o=4hi and o=8+4hi
    float ovA[8], ovB[8];
    if (MODE != 0) {
        const float* pa = ov_in + ((size_t)c * BB + b) * OO + 4 * hi;
        const float* pb = ov_in + ((size_t)c * BB + 32 + b) * OO + 4 * hi;
        float4 a0 = *(const float4*)(pa);
        float4 a1 = *(const float4*)(pa + 8);
        float4 b0 = *(const float4*)(pb);
        float4 b1 = *(const float4*)(pb + 8);
        ovA[0]=a0.x; ovA[1]=a0.y; ovA[2]=a0.z; ovA[3]=a0.w;
        ovA[4]=a1.x; ovA[5]=a1.y; ovA[6]=a1.z; ovA[7]=a1.w;
        ovB[0]=b0.x; ovB[1]=b0.y; ovB[2]=b0.z; ovB[3]=b0.w;
        ovB[4]=b1.x; ovB[5]=b1.y; ovB[6]=b1.z; ovB[7]=b1.w;
    }

    __syncthreads();   // W tile ready

    const int rbase = chunk * RPB + wv * 16;

    f32x16 cA, cB, zf;
#pragma unroll
    for (int q = 0; q < 16; ++q) { cA[q] = 0.f; cB[q] = 0.f; zf[q] = 0.f; }

    // prefetch group 0 x-frags
    HV xc0, xc1, xn0, xn1;
    xc0.v = xth4[(size_t)(rbase + hi) * BB + b];
    xc1.v = xth4[(size_t)(rbase + hi) * BB + 32 + b];
    xn0 = xc0; xn1 = xc1;

#pragma unroll 1
    for (int g = 0; g < NGRP; ++g) {
        if (g + 1 < NGRP) {
            const int rn = rbase + (g + 1) * 2 + hi;
            xn0.v = xth4[(size_t)rn * BB + b];
            xn1.v = xth4[(size_t)rn * BB + 32 + b];
        }
        const int rl0 = wv * 16 + g * 2;
        HV wq;
        wq.v = wlds[(rl0 + aquad) * 16 + (l & 15)];
        if (!aact) wq.v = make_int4(0, 0, 0, 0);

        if (MODE == 0) {
            cA = __builtin_amdgcn_mfma_f32_32x32x16_f16(wq.h8, xc0.h8, cA, 0, 0, 0);
            cB = __builtin_amdgcn_mfma_f32_32x32x16_f16(wq.h8, xc1.h8, cB, 0, 0, 0);
        } else {
            f32x16 p0 = __builtin_amdgcn_mfma_f32_32x32x16_f16(wq.h8, xc0.h8, zf, 0, 0, 0);
            f32x16 p1 = __builtin_amdgcn_mfma_f32_32x32x16_f16(wq.h8, xc1.h8, zf, 0, 0, 0);

            float dA0 = 0.f, dA1 = 0.f, dB0 = 0.f, dB1 = 0.f;
#pragma unroll
            for (int j = 0; j < 8; ++j) {
                dA0 = fmaf(p0[j],     ovA[j], dA0);
                dA1 = fmaf(p0[j + 8], ovA[j], dA1);
                dB0 = fmaf(p1[j],     ovB[j], dB0);
                dB1 = fmaf(p1[j + 8], ovB[j], dB1);
            }
            // partner lane (l^32) holds the complementary o-half for same b
            dA0 += __shfl_xor(dA0, 32);
            dA1 += __shfl_xor(dA1, 32);
            dB0 += __shfl_xor(dB0, 32);
            dB1 += __shfl_xor(dB1, 32);
            const float eA0 = __expf(dA0), eA1 = __expf(dA1);
            const float eB0 = __expf(dB0), eB1 = __expf(dB1);
            ZA += eA0 + eA1; ZB += eB0 + eB1;
#pragma unroll
            for (int j = 0; j < 8; ++j) {
                accA[j] = fmaf(eA0, p0[j], fmaf(eA1, p0[j + 8], accA[j]));
                accB[j] = fmaf(eB0, p1[j], fmaf(eB1, p1[j + 8], accB[j]));
            }
        }
        xc0 = xn0; xc1 = xn1;
    }

    if (MODE == 0) {
#pragma unroll
        for (int j = 0; j < 8; ++j) {
            accA[j] = cA[j] + cA[j + 8];
            accB[j] = cB[j] + cB[j + 8];
        }
    }

    __syncthreads();   // done reading W tile; alias LDS for the merge

    {
        // lane writes its 8 o-slots as two float4s: o = 4hi+{0..3}, 8+4hi+{0..3}
        float* m0 = lds + (wv * 64 + b) * MRG_PAD + 4 * hi;
        *(float4*)(m0)     = make_float4(accA[0], accA[1], accA[2], accA[3]);
        *(float4*)(m0 + 8) = make_float4(accA[4], accA[5], accA[6], accA[7]);
        float* m1 = lds + (wv * 64 + 32 + b) * MRG_PAD + 4 * hi;
        *(float4*)(m1)     = make_float4(accB[0], accB[1], accB[2], accB[3]);
        *(float4*)(m1 + 8) = make_float4(accB[4], accB[5], accB[6], accB[7]);
        if (MODE != 0 && hi == 0) {   // hi=1 holds identical Z
            float* zr = lds + 4 * 64 * MRG_PAD;
            zr[wv * 64 + b] = ZA;
            zr[wv * 64 + 32 + b] = ZB;
        }
    }
    __syncthreads();

    // per-chunk partial store: thread t -> (b2 = t>>2, o-quad q = t&3)
    {
        const int b2 = t >> 2, q = t & 3;
        float4 sum = make_float4(0.f, 0.f, 0.f, 0.f);
#pragma unroll
        for (int w2 = 0; w2 < 4; ++w2) {
            const float4 v = *(const float4*)(lds + (w2 * 64 + b2) * MRG_PAD + q * 4);
            sum.x += v.x; sum.y += v.y; sum.z += v.z; sum.w += v.w;
        }
        *(float4*)(pacc + (((size_t)(c * NCH + chunk) * BB + b2) * OO) + q * 4) = sum;
        if (MODE != 0 && q == 0) {
            const float* zr = lds + 4 * 64 * MRG_PAD;
            float z = 0.f;
#pragma unroll
            for (int w2 = 0; w2 < 4; ++w2) z += zr[w2 * 64 + b2];
            pz[(size_t)(c * NCH + chunk) * BB + b2] = z;
        }
    }

    // ---- fused combine: last block of this class does the reduction ----
    __syncthreads();
    __threadfence();                       // release partials device-wide
    if (t == 0) {
        const int prev = atomicAdd(cnt + c, 1);   // device-scope
        islast = (prev == NCH - 1);
    }
    __syncthreads();
    if (!islast) return;
    __threadfence();                       // acquire: invalidate stale cache

    float s0 = 0.f, s1 = 0.f, s2 = 0.f, s3 = 0.f, zb = 0.f;
    const float* pb  = pacc + (size_t)c * NCH * BB * OO;
    const float* pzb = pz   + (size_t)c * NCH * BB;
#pragma unroll 4
    for (int p = 0; p < NCH; ++p) {
        const float* row = pb + (size_t)p * BB * OO;
        s0 += row[t];
        s1 += row[t + 256];
        s2 += row[t + 512];
        s3 += row[t + 768];
        if (MODE != 0 && t < 64) zb += pzb[p * BB + t];
    }

    float* zl = lds;                       // reuse (all prior LDS use barriered)
    if (MODE != 0) {
        if (t < 64) zl[t] = zb;
        __syncthreads();
    }

    float sk[4] = {s0, s1, s2, s3};
#pragma unroll
    for (int k = 0; k < 4; ++k) {
        const int m = t + 256 * k;         // m = b*16 + o
        float v = sk[k];
        v = (MODE == 0) ? v * (1.0f / RR) : v / zl[m >> 4];
        float sq = v * v;
#pragma unroll
        for (int ww = 1; ww < 16; ww <<= 1) sq += __shfl_xor(sq, ww);
        float val = v * sqrtf(sq) / (1.f + sq);
        if (MODE == 1) val += ov_in[(size_t)c * (BB * OO) + m];  // + out0
        outw[(size_t)c * (BB * OO) + m] = val;
    }
}

extern "C" void kernel_launch(void* const* d_in, const int* in_sizes, int n_in,
                              void* d_out, int out_size, void* d_ws, size_t ws_size,
                              hipStream_t stream)
{
    const float* x = (const float*)d_in[0];
    const float* w = (const float*)d_in[1];
    float* out = (float*)d_out;

    float* ws = (float*)d_ws;
    float* xth    = ws;                                   // RR*BB*8 f16 = RR*BB*4 f32 slots
    float* wh     = xth + (size_t)RR * BB * 4;            // CC*RR*128 f16 = CC*RR*64 f32 slots
    float* pacc   = wh + (size_t)CC * RR * 64;            // CC*NCH*BB*OO
    float* pz     = pacc + (size_t)CC * NCH * BB * OO;    // CC*NCH*BB
    float* out0   = pz + (size_t)CC * NCH * BB;           // CC*BB*OO
    float* outsum = out0 + CC * BB * OO;                  // CC*BB*OO
    int*   cnt    = (int*)(outsum + CC * BB * OO);        // 3*10 counters (+pad)

    int4* xth4 = (int4*)xth;
    int4* wh4  = (int4*)wh;
    const float4* w4 = (const float4*)w;

    prep_kernel<<<dim3(432 + 1080), dim3(256), 0, stream>>>(x, xth4, w4, wh4, cnt);

    const dim3 gp(CC * NCH), bp(256);
    pass_kernel<0><<<gp, bp, 0, stream>>>(xth4, wh4, nullptr, pacc, pz, out0,   cnt);
    pass_kernel<1><<<gp, bp, 0, stream>>>(xth4, wh4, out0,    pacc, pz, outsum, cnt + 10);
    pass_kernel<2><<<gp, bp, 0, stream>>>(xth4, wh4, outsum,  pacc, pz, out,    cnt + 20);
}

// Round 3
// 175.270 us; speedup vs baseline: 2.6503x; 2.6503x over previous
//
#include <hip/hip_runtime.h>
#include <math.h>

#define BB 64
#define RR 6912
#define II 8
#define CC 10
#define OO 16
#define RPB 64          // routes per block
#define NCH 108         // RR / RPB
#define NGRP 8          // 2-route MFMA groups per wave (16 routes/wave x 4 waves)
#define MRG_PAD 20      // merge row stride in floats (pad 16->20 vs bank conflicts)
#define LDSF (4*64*MRG_PAD + 4*64)   // 5376 floats = 21504 B; aliases 16 KB W tile
#define ZTOT (3*CC*BB*OO + 2*CC*BB + 32)   // acc0..2 + z1,z2 + cnt = 32032 words

typedef _Float16 h2 __attribute__((ext_vector_type(2)));
typedef _Float16 half8 __attribute__((ext_vector_type(8)));
typedef float f32x16 __attribute__((ext_vector_type(16)));
union HV { int4 v; h2 h[4]; half8 h8; };

// ---------------- prep kernel ----------------
// blocks [0,432): transpose+cvt x[B][R][8] f32 -> xth[R][B][8] f16
// blocks [432,1512): W convert  W[c][r][i][o] f32 -> wh[c][r][o][i] f16
// All blocks: zero a 32-word slice of the accumulator/counter region (no
// separate memset dispatch). Visible to pass via inter-dispatch flush.
__global__ __launch_bounds__(256) void prep_kernel(
    const float* __restrict__ x, int4* __restrict__ xth4,
    const float4* __restrict__ w4, int4* __restrict__ wh4,
    float* __restrict__ zr)
{
    __shared__ __align__(16) float4 lds4[64 * 34];   // 34816 B; wcvt aliases 8 KB
    const int t = threadIdx.x;
    const int bid = blockIdx.x;

    if (t < 32) {
        const unsigned idx = (unsigned)bid * 32u + (unsigned)t;
        if (idx < (unsigned)ZTOT) zr[idx] = 0.f;
    }

    if (bid < 432) {
        // ---- transpose+cvt ----
        const int rblk = bid >> 2;
        const int bblk = bid & 3;
        const int r0 = rblk * 64, b0 = bblk * 16;
        {
            const int rl = t & 63;
            const int bl0 = t >> 6;
#pragma unroll
            for (int kb = 0; kb < 4; ++kb) {
                const int bl = kb * 4 + bl0;
                const float4* src = (const float4*)(x + ((size_t)(b0 + bl) * RR + (r0 + rl)) * II);
                lds4[rl * 34 + bl * 2 + 0] = src[0];
                lds4[rl * 34 + bl * 2 + 1] = src[1];
            }
        }
        __syncthreads();
        {
            const int bl = t & 15;
            const int rw0 = t >> 4;
#pragma unroll
            for (int kr = 0; kr < 4; ++kr) {
                const int rw = kr * 16 + rw0;
                float4 a = lds4[rw * 34 + bl * 2 + 0];
                float4 bq = lds4[rw * 34 + bl * 2 + 1];
                HV u;
                u.h[0] = h2{(_Float16)a.x,  (_Float16)a.y};
                u.h[1] = h2{(_Float16)a.z,  (_Float16)a.w};
                u.h[2] = h2{(_Float16)bq.x, (_Float16)bq.y};
                u.h[3] = h2{(_Float16)bq.z, (_Float16)bq.w};
                xth4[(size_t)(r0 + rw) * BB + (b0 + bl)] = u.v;
            }
        }
    } else {
        // ---- W convert: 8 sub-tiles of 8 routes, double-buffered LDS ----
        _Float16* wl = (_Float16*)lds4;
        const int wblk = bid - 432;          // 0..1079
        const int rp = t >> 5;
        const int i  = (t >> 2) & 7;
        const int o0 = (t & 3) * 4;
#pragma unroll 1
        for (int sb = 0; sb < 8; ++sb) {
            const int blk8 = wblk * 8 + sb;  // == c*864 + (r/8)
            const float4 v = w4[(size_t)blk8 * 256 + t];
            _Float16* wb = wl + (sb & 1) * 1024;
            wb[(rp * 16 + o0 + 0) * 8 + i] = (_Float16)v.x;
            wb[(rp * 16 + o0 + 1) * 8 + i] = (_Float16)v.y;
            wb[(rp * 16 + o0 + 2) * 8 + i] = (_Float16)v.z;
            wb[(rp * 16 + o0 + 3) * 8 + i] = (_Float16)v.w;
            __syncthreads();
            if (t < 128) wh4[(size_t)blk8 * 128 + t] = ((const int4*)wb)[t];
        }
    }
}

// ---------------- pass kernel (MFMA, fused combine via atomics) ----------------
// Per block: one (c, 64-route chunk). W tile staged once in LDS (16 KB, f16
// [r][o][i]). MFMA structure: see R1 notes. Cross-block combine uses ONLY
// device-scope atomics (execute at the coherent memory side, bypass the
// non-coherent per-XCD L2s) -> no threadfence / buffer_wbl2 anywhere:
//   - block partial (1024 f32 + 64 Z) atomicAdd'ed into per-class accumulator
//   - __syncthreads() drains vmcnt (barrier semantics) => release ordering
//   - atomicAdd(cnt+c) elects the last block, which reads the sums back with
//     atomicAdd(p, 0.0f) (coherent RMW), squashes, and writes the output the
//     next stream-ordered dispatch consumes.
template <int MODE>
__global__ __launch_bounds__(256, 4) void pass_kernel(
    const int4* __restrict__ xth4, const int4* __restrict__ wh4,
    const float* __restrict__ ov_in,
    float* __restrict__ accg, float* __restrict__ zg,
    float* __restrict__ outw, int* __restrict__ cnt)
{
    __shared__ __align__(16) float lds[LDSF];
    __shared__ int islast;
    int4* wlds = (int4*)lds;

    // XCD-affinity swizzle (1080 = 8*135, bijective): the 10 c-blocks sharing
    // a chunk's x-tile land on one XCD's L2.
    const int bid = blockIdx.x;
    const int w = (bid & 7) * 135 + (bid >> 3);
    const int chunk = w / 10;
    const int c = w - chunk * 10;

    const int t = threadIdx.x;
    const int wv = t >> 6;
    const int l = t & 63;
    const int b = l & 31;
    const int hi = l >> 5;
    const int aquad = (l >> 4) & 1;
    const bool aact = (aquad == hi);

    // stage the 64-route W tile: 256 threads x 4 int4, coalesced
    {
        const int4* src = wh4 + (size_t)(c * (RR / 8) + chunk * 8) * 128;
#pragma unroll
        for (int k = 0; k < 4; ++k) wlds[k * 256 + t] = src[k * 256 + t];
    }

    float accA[8], accB[8];
#pragma unroll
    for (int j = 0; j < 8; ++j) { accA[j] = 0.f; accB[j] = 0.f; }
    float ZA = 0.f, ZB = 0.f;

    // ov gather: lane needs out_prev[b][o] for its 8 o-slots
    // o(j,hi) = (j&3) + 8*(j>>2) + 4*hi  -> two float4s at o=4hi and o=8+4hi
    float ovA[8], ovB[8];
    if (MODE != 0) {
        const float* pa = ov_in + ((size_t)c * BB + b) * OO + 4 * hi;
        const float* pb = ov_in + ((size_t)c * BB + 32 + b) * OO + 4 * hi;
        float4 a0 = *(const float4*)(pa);
        float4 a1 = *(const float4*)(pa + 8);
        float4 b0 = *(const float4*)(pb);
        float4 b1 = *(const float4*)(pb + 8);
        ovA[0]=a0.x; ovA[1]=a0.y; ovA[2]=a0.z; ovA[3]=a0.w;
        ovA[4]=a1.x; ovA[5]=a1.y; ovA[6]=a1.z; ovA[7]=a1.w;
        ovB[0]=b0.x; ovB[1]=b0.y; ovB[2]=b0.z; ovB[3]=b0.w;
        ovB[4]=b1.x; ovB[5]=b1.y; ovB[6]=b1.z; ovB[7]=b1.w;
    }

    __syncthreads();   // W tile ready

    const int rbase = chunk * RPB + wv * 16;

    f32x16 cA, cB, zf;
#pragma unroll
    for (int q = 0; q < 16; ++q) { cA[q] = 0.f; cB[q] = 0.f; zf[q] = 0.f; }

    // prefetch group 0 x-frags
    HV xc0, xc1, xn0, xn1;
    xc0.v = xth4[(size_t)(rbase + hi) * BB + b];
    xc1.v = xth4[(size_t)(rbase + hi) * BB + 32 + b];
    xn0 = xc0; xn1 = xc1;

#pragma unroll 1
    for (int g = 0; g < NGRP; ++g) {
        if (g + 1 < NGRP) {
            const int rn = rbase + (g + 1) * 2 + hi;
            xn0.v = xth4[(size_t)rn * BB + b];
            xn1.v = xth4[(size_t)rn * BB + 32 + b];
        }
        const int rl0 = wv * 16 + g * 2;
        HV wq;
        wq.v = wlds[(rl0 + aquad) * 16 + (l & 15)];
        if (!aact) wq.v = make_int4(0, 0, 0, 0);

        if (MODE == 0) {
            cA = __builtin_amdgcn_mfma_f32_32x32x16_f16(wq.h8, xc0.h8, cA, 0, 0, 0);
            cB = __builtin_amdgcn_mfma_f32_32x32x16_f16(wq.h8, xc1.h8, cB, 0, 0, 0);
        } else {
            f32x16 p0 = __builtin_amdgcn_mfma_f32_32x32x16_f16(wq.h8, xc0.h8, zf, 0, 0, 0);
            f32x16 p1 = __builtin_amdgcn_mfma_f32_32x32x16_f16(wq.h8, xc1.h8, zf, 0, 0, 0);

            float dA0 = 0.f, dA1 = 0.f, dB0 = 0.f, dB1 = 0.f;
#pragma unroll
            for (int j = 0; j < 8; ++j) {
                dA0 = fmaf(p0[j],     ovA[j], dA0);
                dA1 = fmaf(p0[j + 8], ovA[j], dA1);
                dB0 = fmaf(p1[j],     ovB[j], dB0);
                dB1 = fmaf(p1[j + 8], ovB[j], dB1);
            }
            // partner lane (l^32) holds the complementary o-half for same b
            dA0 += __shfl_xor(dA0, 32);
            dA1 += __shfl_xor(dA1, 32);
            dB0 += __shfl_xor(dB0, 32);
            dB1 += __shfl_xor(dB1, 32);
            const float eA0 = __expf(dA0), eA1 = __expf(dA1);
            const float eB0 = __expf(dB0), eB1 = __expf(dB1);
            ZA += eA0 + eA1; ZB += eB0 + eB1;
#pragma unroll
            for (int j = 0; j < 8; ++j) {
                accA[j] = fmaf(eA0, p0[j], fmaf(eA1, p0[j + 8], accA[j]));
                accB[j] = fmaf(eB0, p1[j], fmaf(eB1, p1[j + 8], accB[j]));
            }
        }
        xc0 = xn0; xc1 = xn1;
    }

    if (MODE == 0) {
#pragma unroll
        for (int j = 0; j < 8; ++j) {
            accA[j] = cA[j] + cA[j + 8];
            accB[j] = cB[j] + cB[j + 8];
        }
    }

    __syncthreads();   // done reading W tile; alias LDS for the merge

    {
        // lane writes its 8 o-slots as two float4s: o = 4hi+{0..3}, 8+4hi+{0..3}
        float* m0 = lds + (wv * 64 + b) * MRG_PAD + 4 * hi;
        *(float4*)(m0)     = make_float4(accA[0], accA[1], accA[2], accA[3]);
        *(float4*)(m0 + 8) = make_float4(accA[4], accA[5], accA[6], accA[7]);
        float* m1 = lds + (wv * 64 + 32 + b) * MRG_PAD + 4 * hi;
        *(float4*)(m1)     = make_float4(accB[0], accB[1], accB[2], accB[3]);
        *(float4*)(m1 + 8) = make_float4(accB[4], accB[5], accB[6], accB[7]);
        if (MODE != 0 && hi == 0) {   // hi=1 holds identical Z
            float* zr = lds + 4 * 64 * MRG_PAD;
            zr[wv * 64 + b] = ZA;
            zr[wv * 64 + 32 + b] = ZB;
        }
    }
    __syncthreads();

    // per-chunk partial -> per-class accumulator via device-scope atomicAdd
    {
        const int b2 = t >> 2, q = t & 3;
        float4 sum = make_float4(0.f, 0.f, 0.f, 0.f);
#pragma unroll
        for (int w2 = 0; w2 < 4; ++w2) {
            const float4 v = *(const float4*)(lds + (w2 * 64 + b2) * MRG_PAD + q * 4);
            sum.x += v.x; sum.y += v.y; sum.z += v.z; sum.w += v.w;
        }
        float* dst = accg + ((size_t)c * BB + b2) * OO + q * 4;
        atomicAdd(dst + 0, sum.x);
        atomicAdd(dst + 1, sum.y);
        atomicAdd(dst + 2, sum.z);
        atomicAdd(dst + 3, sum.w);
        if (MODE != 0 && q == 0) {
            const float* zr = lds + 4 * 64 * MRG_PAD;
            float z = 0.f;
#pragma unroll
            for (int w2 = 0; w2 < 4; ++w2) z += zr[w2 * 64 + b2];
            atomicAdd(zg + (size_t)c * BB + b2, z);
        }
    }

    // release: __syncthreads() drains vmcnt(0) in every wave -> all data
    // atomics completed at the coherence point before the counter bump.
    __syncthreads();
    if (t == 0) islast = (atomicAdd(cnt + c, 1) == NCH - 1);
    __syncthreads();
    if (!islast) return;

    // ---- last block of class c: coherent read-back + squash + output ----
    float sk[4];
    float* accC = accg + (size_t)c * BB * OO;
#pragma unroll
    for (int k = 0; k < 4; ++k) sk[k] = atomicAdd(accC + t + 256 * k, 0.0f);

    float* zl = lds;                       // reuse (all prior LDS use barriered)
    if (MODE != 0) {
        if (t < 64) zl[t] = atomicAdd(zg + (size_t)c * BB + t, 0.0f);
        __syncthreads();
    }

#pragma unroll
    for (int k = 0; k < 4; ++k) {
        const int m = t + 256 * k;         // m = b*16 + o
        float v = sk[k];
        v = (MODE == 0) ? v * (1.0f / RR) : v / zl[m >> 4];
        float sq = v * v;
#pragma unroll
        for (int ww = 1; ww < 16; ww <<= 1) sq += __shfl_xor(sq, ww);
        float val = v * sqrtf(sq) / (1.f + sq);
        if (MODE == 1) val += ov_in[(size_t)c * (BB * OO) + m];  // + out0
        outw[(size_t)c * (BB * OO) + m] = val;
    }
}

extern "C" void kernel_launch(void* const* d_in, const int* in_sizes, int n_in,
                              void* d_out, int out_size, void* d_ws, size_t ws_size,
                              hipStream_t stream)
{
    const float* x = (const float*)d_in[0];
    const float* w = (const float*)d_in[1];
    float* out = (float*)d_out;

    float* ws = (float*)d_ws;
    float* xth    = ws;                                   // RR*BB*8 f16 = RR*BB*4 f32 slots
    float* wh     = xth + (size_t)RR * BB * 4;            // CC*RR*128 f16 = CC*RR*64 f32 slots
    float* acc0   = wh + (size_t)CC * RR * 64;            // CC*BB*OO   (zeroed by prep)
    float* acc1   = acc0 + CC * BB * OO;                  // CC*BB*OO
    float* acc2   = acc1 + CC * BB * OO;                  // CC*BB*OO
    float* z1     = acc2 + CC * BB * OO;                  // CC*BB
    float* z2     = z1 + CC * BB;                         // CC*BB
    int*   cnt    = (int*)(z2 + CC * BB);                 // 3x10 counters (+pad)
    float* out0   = (float*)(cnt + 32);                   // CC*BB*OO
    float* outsum = out0 + CC * BB * OO;                  // CC*BB*OO

    int4* xth4 = (int4*)xth;
    int4* wh4  = (int4*)wh;
    const float4* w4 = (const float4*)w;

    prep_kernel<<<dim3(432 + 1080), dim3(256), 0, stream>>>(x, xth4, w4, wh4, acc0);

    const dim3 gp(CC * NCH), bp(256);
    pass_kernel<0><<<gp, bp, 0, stream>>>(xth4, wh4, nullptr, acc0, nullptr, out0,   cnt);
    pass_kernel<1><<<gp, bp, 0, stream>>>(xth4, wh4, out0,    acc1, z1,      outsum, cnt + 10);
    pass_kernel<2><<<gp, bp, 0, stream>>>(xth4, wh4, outsum,  acc2, z2,      out,    cnt + 20);
}

// Round 4
// 136.125 us; speedup vs baseline: 3.4124x; 1.2876x over previous
//
#include <hip/hip_runtime.h>
#include <math.h>

#define BB 64
#define RR 6912
#define II 8
#define CC 10
#define OO 16
#define RPB 64          // routes per block
#define NCH 108         // RR / RPB
#define NGRP 8          // 2-route MFMA groups per wave (16 routes/wave x 4 waves)
#define MRG_PAD 20      // merge row stride in floats (pad 16->20 vs bank conflicts)
#define LDSF (4*64*MRG_PAD + 4*64)   // 5376 floats = 21504 B; aliases 16 KB W tile

typedef _Float16 h2 __attribute__((ext_vector_type(2)));
typedef _Float16 half8 __attribute__((ext_vector_type(8)));
typedef float f32x16 __attribute__((ext_vector_type(16)));
union HV { int4 v; h2 h[4]; half8 h8; };

// ---------------- prep kernel ----------------
// blocks [0,432): transpose+cvt x[B][R][8] f32 -> xth[R][B][8] f16
// blocks [432,1512): W convert  W[c][r][i][o] f32 -> wh[c][r][o][i] f16
//                    (each block handles 64 routes = 8 sub-tiles, dbuf LDS)
__global__ __launch_bounds__(256) void prep_kernel(
    const float* __restrict__ x, int4* __restrict__ xth4,
    const float4* __restrict__ w4, int4* __restrict__ wh4)
{
    __shared__ __align__(16) float4 lds4[64 * 34];   // 34816 B; wcvt aliases 8 KB
    const int t = threadIdx.x;
    const int bid = blockIdx.x;

    if (bid < 432) {
        // ---- transpose+cvt ----
        const int rblk = bid >> 2;
        const int bblk = bid & 3;
        const int r0 = rblk * 64, b0 = bblk * 16;
        {
            const int rl = t & 63;
            const int bl0 = t >> 6;
#pragma unroll
            for (int kb = 0; kb < 4; ++kb) {
                const int bl = kb * 4 + bl0;
                const float4* src = (const float4*)(x + ((size_t)(b0 + bl) * RR + (r0 + rl)) * II);
                lds4[rl * 34 + bl * 2 + 0] = src[0];
                lds4[rl * 34 + bl * 2 + 1] = src[1];
            }
        }
        __syncthreads();
        {
            const int bl = t & 15;
            const int rw0 = t >> 4;
#pragma unroll
            for (int kr = 0; kr < 4; ++kr) {
                const int rw = kr * 16 + rw0;
                float4 a = lds4[rw * 34 + bl * 2 + 0];
                float4 bq = lds4[rw * 34 + bl * 2 + 1];
                HV u;
                u.h[0] = h2{(_Float16)a.x,  (_Float16)a.y};
                u.h[1] = h2{(_Float16)a.z,  (_Float16)a.w};
                u.h[2] = h2{(_Float16)bq.x, (_Float16)bq.y};
                u.h[3] = h2{(_Float16)bq.z, (_Float16)bq.w};
                xth4[(size_t)(r0 + rw) * BB + (b0 + bl)] = u.v;
            }
        }
    } else {
        // ---- W convert: 8 sub-tiles of 8 routes, double-buffered LDS ----
        _Float16* wl = (_Float16*)lds4;
        const int wblk = bid - 432;          // 0..1079
        const int rp = t >> 5;
        const int i  = (t >> 2) & 7;
        const int o0 = (t & 3) * 4;
#pragma unroll 1
        for (int sb = 0; sb < 8; ++sb) {
            const int blk8 = wblk * 8 + sb;  // == c*864 + (r/8)
            const float4 v = w4[(size_t)blk8 * 256 + t];
            _Float16* wb = wl + (sb & 1) * 1024;
            wb[(rp * 16 + o0 + 0) * 8 + i] = (_Float16)v.x;
            wb[(rp * 16 + o0 + 1) * 8 + i] = (_Float16)v.y;
            wb[(rp * 16 + o0 + 2) * 8 + i] = (_Float16)v.z;
            wb[(rp * 16 + o0 + 3) * 8 + i] = (_Float16)v.w;
            __syncthreads();
            if (t < 128) wh4[(size_t)blk8 * 128 + t] = ((const int4*)wb)[t];
        }
    }
}

// ---------------- pass kernel (MFMA) ----------------
// Per block: one (c, 64-route chunk). W tile staged once in LDS (16 KB, f16
// [r][o][i]). Each wave owns 16 routes = 8 groups of 2 routes packed
// block-diagonally into v_mfma_f32_32x32x16_f16:
//   A[o'=2rx16o, k=2rx8i], B[k, b], C[o', b] (layouts: see R1 notes).
// Plain-store per-chunk partials to pacc/pz; separate combine kernel reduces.
template <int MODE>
__global__ __launch_bounds__(256, 4) void pass_kernel(
    const int4* __restrict__ xth4, const int4* __restrict__ wh4,
    const float* __restrict__ ov_in,
    float* __restrict__ pacc, float* __restrict__ pz)
{
    __shared__ __align__(16) float lds[LDSF];
    int4* wlds = (int4*)lds;

    // XCD-affinity swizzle (1080 = 8*135, bijective): the 10 c-blocks sharing
    // a chunk's x-tile land on one XCD's L2.
    const int bid = blockIdx.x;
    const int w = (bid & 7) * 135 + (bid >> 3);
    const int chunk = w / 10;
    const int c = w - chunk * 10;

    const int t = threadIdx.x;
    const int wv = t >> 6;
    const int l = t & 63;
    const int b = l & 31;
    const int hi = l >> 5;
    const int aquad = (l >> 4) & 1;
    const bool aact = (aquad == hi);

    // stage the 64-route W tile: 256 threads x 4 int4, coalesced
    {
        const int4* src = wh4 + (size_t)(c * (RR / 8) + chunk * 8) * 128;
#pragma unroll
        for (int k = 0; k < 4; ++k) wlds[k * 256 + t] = src[k * 256 + t];
    }

    float accA[8], accB[8];
#pragma unroll
    for (int j = 0; j < 8; ++j) { accA[j] = 0.f; accB[j] = 0.f; }
    float ZA = 0.f, ZB = 0.f;

    // ov gather: lane needs out_prev[b][o] for its 8 o-slots
    // o(j,hi) = (j&3) + 8*(j>>2) + 4*hi  -> two float4s at o=4hi and o=8+4hi
    float ovA[8], ovB[8];
    if (MODE != 0) {
        const float* pa = ov_in + ((size_t)c * BB + b) * OO + 4 * hi;
        const float* pb = ov_in + ((size_t)c * BB + 32 + b) * OO + 4 * hi;
        float4 a0 = *(const float4*)(pa);
        float4 a1 = *(const float4*)(pa + 8);
        float4 b0 = *(const float4*)(pb);
        float4 b1 = *(const float4*)(pb + 8);
        ovA[0]=a0.x; ovA[1]=a0.y; ovA[2]=a0.z; ovA[3]=a0.w;
        ovA[4]=a1.x; ovA[5]=a1.y; ovA[6]=a1.z; ovA[7]=a1.w;
        ovB[0]=b0.x; ovB[1]=b0.y; ovB[2]=b0.z; ovB[3]=b0.w;
        ovB[4]=b1.x; ovB[5]=b1.y; ovB[6]=b1.z; ovB[7]=b1.w;
    }

    __syncthreads();   // W tile ready

    const int rbase = chunk * RPB + wv * 16;

    f32x16 cA, cB, zf;
#pragma unroll
    for (int q = 0; q < 16; ++q) { cA[q] = 0.f; cB[q] = 0.f; zf[q] = 0.f; }

    // prefetch group 0 x-frags
    HV xc0, xc1, xn0, xn1;
    xc0.v = xth4[(size_t)(rbase + hi) * BB + b];
    xc1.v = xth4[(size_t)(rbase + hi) * BB + 32 + b];
    xn0 = xc0; xn1 = xc1;

#pragma unroll 1
    for (int g = 0; g < NGRP; ++g) {
        if (g + 1 < NGRP) {
            const int rn = rbase + (g + 1) * 2 + hi;
            xn0.v = xth4[(size_t)rn * BB + b];
            xn1.v = xth4[(size_t)rn * BB + 32 + b];
        }
        const int rl0 = wv * 16 + g * 2;
        HV wq;
        wq.v = wlds[(rl0 + aquad) * 16 + (l & 15)];
        if (!aact) wq.v = make_int4(0, 0, 0, 0);

        if (MODE == 0) {
            cA = __builtin_amdgcn_mfma_f32_32x32x16_f16(wq.h8, xc0.h8, cA, 0, 0, 0);
            cB = __builtin_amdgcn_mfma_f32_32x32x16_f16(wq.h8, xc1.h8, cB, 0, 0, 0);
        } else {
            f32x16 p0 = __builtin_amdgcn_mfma_f32_32x32x16_f16(wq.h8, xc0.h8, zf, 0, 0, 0);
            f32x16 p1 = __builtin_amdgcn_mfma_f32_32x32x16_f16(wq.h8, xc1.h8, zf, 0, 0, 0);

            float dA0 = 0.f, dA1 = 0.f, dB0 = 0.f, dB1 = 0.f;
#pragma unroll
            for (int j = 0; j < 8; ++j) {
                dA0 = fmaf(p0[j],     ovA[j], dA0);
                dA1 = fmaf(p0[j + 8], ovA[j], dA1);
                dB0 = fmaf(p1[j],     ovB[j], dB0);
                dB1 = fmaf(p1[j + 8], ovB[j], dB1);
            }
            // partner lane (l^32) holds the complementary o-half for same b
            dA0 += __shfl_xor(dA0, 32);
            dA1 += __shfl_xor(dA1, 32);
            dB0 += __shfl_xor(dB0, 32);
            dB1 += __shfl_xor(dB1, 32);
            const float eA0 = __expf(dA0), eA1 = __expf(dA1);
            const float eB0 = __expf(dB0), eB1 = __expf(dB1);
            ZA += eA0 + eA1; ZB += eB0 + eB1;
#pragma unroll
            for (int j = 0; j < 8; ++j) {
                accA[j] = fmaf(eA0, p0[j], fmaf(eA1, p0[j + 8], accA[j]));
                accB[j] = fmaf(eB0, p1[j], fmaf(eB1, p1[j + 8], accB[j]));
            }
        }
        xc0 = xn0; xc1 = xn1;
    }

    if (MODE == 0) {
#pragma unroll
        for (int j = 0; j < 8; ++j) {
            accA[j] = cA[j] + cA[j + 8];
            accB[j] = cB[j] + cB[j + 8];
        }
    }

    __syncthreads();   // done reading W tile; alias LDS for the merge

    {
        // lane writes its 8 o-slots as two float4s: o = 4hi+{0..3}, 8+4hi+{0..3}
        float* m0 = lds + (wv * 64 + b) * MRG_PAD + 4 * hi;
        *(float4*)(m0)     = make_float4(accA[0], accA[1], accA[2], accA[3]);
        *(float4*)(m0 + 8) = make_float4(accA[4], accA[5], accA[6], accA[7]);
        float* m1 = lds + (wv * 64 + 32 + b) * MRG_PAD + 4 * hi;
        *(float4*)(m1)     = make_float4(accB[0], accB[1], accB[2], accB[3]);
        *(float4*)(m1 + 8) = make_float4(accB[4], accB[5], accB[6], accB[7]);
        if (MODE != 0 && hi == 0) {   // hi=1 holds identical Z
            float* zr = lds + 4 * 64 * MRG_PAD;
            zr[wv * 64 + b] = ZA;
            zr[wv * 64 + 32 + b] = ZB;
        }
    }
    __syncthreads();

    // per-chunk partial store: thread t -> (b2 = t>>2, o-quad q = t&3)
    {
        const int b2 = t >> 2, q = t & 3;
        float4 sum = make_float4(0.f, 0.f, 0.f, 0.f);
#pragma unroll
        for (int w2 = 0; w2 < 4; ++w2) {
            const float4 v = *(const float4*)(lds + (w2 * 64 + b2) * MRG_PAD + q * 4);
            sum.x += v.x; sum.y += v.y; sum.z += v.z; sum.w += v.w;
        }
        *(float4*)(pacc + (((size_t)(c * NCH + chunk) * BB + b2) * OO) + q * 4) = sum;
        if (MODE != 0 && q == 0) {
            const float* zr = lds + 4 * 64 * MRG_PAD;
            float z = 0.f;
#pragma unroll
            for (int w2 = 0; w2 < 4; ++w2) z += zr[w2 * 64 + b2];
            pz[(size_t)(c * NCH + chunk) * BB + b2] = z;
        }
    }
}

// ---------------- combine kernel ----------------
// One block per (c,b). 256 threads = 16 o x 16 groups. Plain sums (no max).
template <int MODE>
__global__ __launch_bounds__(256) void combine_kernel(
    const float* __restrict__ pacc, const float* __restrict__ pz,
    const float* __restrict__ out0, float* __restrict__ outw)
{
    __shared__ float lsum[256];
    __shared__ float lz[16];
    const int cb = blockIdx.x;
    const int c = cb >> 6, b = cb & 63;
    const int t = threadIdx.x;
    const int o = t & 15, g = t >> 4;

    float s = 0.f, zl = 0.f;
    for (int p = g; p < NCH; p += 16) {
        s += pacc[((size_t)(c * NCH + p) * BB + b) * OO + o];
        if (MODE != 0 && o == 0) zl += pz[(size_t)(c * NCH + p) * BB + b];
    }
    lsum[t] = s;
    if (MODE != 0 && o == 0) lz[g] = zl;
    __syncthreads();

    if (g == 0) {
#pragma unroll
        for (int k = 1; k < 16; ++k) s += lsum[k * 16 + o];
        if (MODE != 0) {
            float Zt = 0.f;
#pragma unroll
            for (int k = 0; k < 16; ++k) Zt += lz[k];
            s /= Zt;
        } else {
            s *= (1.0f / RR);
        }
        float sq = s * s;
#pragma unroll
        for (int w = 1; w < 16; w <<= 1) sq += __shfl_xor(sq, w);
        float val = s * sqrtf(sq) / (1.f + sq);
        if (MODE == 1) val += out0[(size_t)cb * OO + o];
        outw[(size_t)cb * OO + o] = val;
    }
}

extern "C" void kernel_launch(void* const* d_in, const int* in_sizes, int n_in,
                              void* d_out, int out_size, void* d_ws, size_t ws_size,
                              hipStream_t stream)
{
    const float* x = (const float*)d_in[0];
    const float* w = (const float*)d_in[1];
    float* out = (float*)d_out;

    float* ws = (float*)d_ws;
    float* xth    = ws;                                   // RR*BB*8 f16 = RR*BB*4 f32 slots
    float* wh     = xth + (size_t)RR * BB * 4;            // CC*RR*128 f16 = CC*RR*64 f32 slots
    float* pacc   = wh + (size_t)CC * RR * 64;            // CC*NCH*BB*OO
    float* pz     = pacc + (size_t)CC * NCH * BB * OO;    // CC*NCH*BB
    float* out0   = pz + (size_t)CC * NCH * BB;           // CC*BB*OO
    float* outsum = out0 + CC * BB * OO;                  // CC*BB*OO

    int4* xth4 = (int4*)xth;
    int4* wh4  = (int4*)wh;
    const float4* w4 = (const float4*)w;

    prep_kernel<<<dim3(432 + 1080), dim3(256), 0, stream>>>(x, xth4, w4, wh4);

    const dim3 gp(CC * NCH), bp(256);
    const dim3 gc(CC * BB), bc(256);

    pass_kernel<0><<<gp, bp, 0, stream>>>(xth4, wh4, nullptr, pacc, pz);
    combine_kernel<0><<<gc, bc, 0, stream>>>(pacc, pz, nullptr, out0);
    pass_kernel<1><<<gp, bp, 0, stream>>>(xth4, wh4, out0, pacc, pz);
    combine_kernel<1><<<gc, bc, 0, stream>>>(pacc, pz, out0, outsum);
    pass_kernel<2><<<gp, bp, 0, stream>>>(xth4, wh4, outsum, pacc, pz);
    combine_kernel<2><<<gc, bc, 0, stream>>>(pacc, pz, nullptr, out);
}